// Round 12
// baseline (1229.149 us; speedup 1.0000x reference)
//
#include <hip/hip_runtime.h>

#define B_    1024
#define T_    256
#define LOCN  40001
#define E_    100
#define H_    100
#define NC    600   // [0,400): gates (i|f|g|o) preact, [400,500): t preact, [500,600): s preact

typedef float f32x2 __attribute__((ext_vector_type(2)));

// Fast sigmoid: rcp(1 + exp2(-x*log2e)). v_exp_f32 + v_rcp_f32 are ~1 ulp.
__device__ __forceinline__ float fsig(float x) {
    const float e = __builtin_amdgcn_exp2f(x * -1.442695040888963f);
    return __builtin_amdgcn_rcpf(1.f + e);
}

// ---------------------------------------------------------------------------
// Kernel 1: P_loc[LOC][600] = emb_loc @ [W_ih | W_xt | W_xs] + [b | b_t | b_s]
// (round-0 proven version, PROWS=16)
// ---------------------------------------------------------------------------
constexpr int PROWS = 16;
constexpr int PPAD  = 20;   // pad 16->20 dwords: keeps 16B alignment for b128, breaks pow2 bank stride

__global__ __launch_bounds__(320) void proj_loc_kernel(
    const float* __restrict__ emb_loc,
    const float* __restrict__ W_ih,   // [100][400]
    const float* __restrict__ W_xt,   // [100][100]
    const float* __restrict__ W_xs,   // [100][100]
    const float* __restrict__ b,      // [400]
    const float* __restrict__ b_t,    // [100]
    const float* __restrict__ b_s,    // [100]
    float* __restrict__ P)            // [LOC][600]
{
    __shared__ __attribute__((aligned(16))) float aT[E_][PPAD];  // transposed tile
    const int tid  = threadIdx.x;
    const int row0 = blockIdx.x * PROWS;

    for (int i = tid; i < PROWS * E_; i += 320) {
        int r = i / E_, k = i - r * E_;
        int rr = row0 + r;
        float v = 0.f;
        if (rr < LOCN) v = emb_loc[rr * E_ + k];
        aT[k][r] = v;
    }
    __syncthreads();
    if (tid >= 300) return;

    for (int cc = 0; cc < 2; ++cc) {
        const int c = tid + cc * 300;
        const float* wp; int stride; float bias;
        if (c < 400)      { wp = W_ih + c;         stride = 400; bias = b[c]; }
        else if (c < 500) { wp = W_xt + (c - 400); stride = 100; bias = b_t[c - 400]; }
        else              { wp = W_xs + (c - 500); stride = 100; bias = b_s[c - 500]; }

        float acc[PROWS];
        #pragma unroll
        for (int r = 0; r < PROWS; ++r) acc[r] = bias;

        for (int k = 0; k < E_; ++k) {
            float w = wp[(size_t)k * stride];
            #pragma unroll
            for (int r = 0; r < PROWS; ++r) acc[r] += aT[k][r] * w;
        }
        #pragma unroll
        for (int r = 0; r < PROWS; ++r) {
            int rr = row0 + r;
            if (rr < LOCN) P[(size_t)rr * NC + c] = acc[r];
        }
    }
}

// ---------------------------------------------------------------------------
// Kernel 2: P_t[92][100] = emb_t @ W_tt ; P_s[92][100] = emb_s @ W_ss
// ---------------------------------------------------------------------------
__global__ void proj_ts_kernel(
    const float* __restrict__ emb_t, const float* __restrict__ emb_s,
    const float* __restrict__ W_tt,  const float* __restrict__ W_ss,
    float* __restrict__ P_t, float* __restrict__ P_s)
{
    int idx = blockIdx.x * 256 + threadIdx.x;
    if (idx >= 2 * 92 * H_) return;
    int which = idx / (92 * H_);
    int rem   = idx - which * (92 * H_);
    int r = rem / H_, c = rem - r * H_;
    const float* e = which ? emb_s : emb_t;
    const float* W = which ? W_ss : W_tt;
    float acc = 0.f;
    #pragma unroll
    for (int k = 0; k < 12; ++k) acc += e[r * 12 + k] * W[k * H_ + c];
    (which ? P_s : P_t)[rem] = acc;
}

// ---------------------------------------------------------------------------
// Kernel 3: the recurrence. Round-10 frame (RB=4, NT=704, grid=256, two
// __syncthreads, pk-FMA -- 619 us). DIAGNOSIS after R10/R11: VALU ~2600 cyc
// and LDS ~2700-5000 cyc/step, yet step = 5800 cyc in BOTH -> ~2500-3000 cyc
// of pure latency stall from per-step dependent global-load chains
// (ts: int->Pq->gp; gate: gacc gather), unhideable at 1 block/CU.
// THIS ROUND (latency removal only, no re-scheduling, __syncthreads kept):
//  - ts int streams staged to LDS once (32 KB, slots pre-converted to float)
//  - P_t/P_s staged to LDS once (73.6 KB) -> dependent Pq leg is LDS-local
//  - gacc & gp gathers prefetched ONE STEP AHEAD (register double-buffer)
//    via a 3-slot rotating loc buffer (loc[t]/loc[t+1]/loc[t+2]; no aliasing)
// LDS total ~117.6 KB (<160 KB; R4 proved >64 KB static works). Occupancy
// was 1 block/CU regardless (register-capped).
// ---------------------------------------------------------------------------
constexpr int RB = 4;
constexpr int NT = 704;

__global__ __launch_bounds__(NT, 3) void lstm_rec_kernel(
    const int* __restrict__ traj,
    const int* __restrict__ traj_len_p,
    const int* __restrict__ tu,      const int* __restrict__ tl,
    const int* __restrict__ tu_slot, const int* __restrict__ tl_slot,
    const int* __restrict__ su,      const int* __restrict__ sl,
    const int* __restrict__ su_slot, const int* __restrict__ sl_slot,
    const float* __restrict__ P,     // [LOC][600]
    const float* __restrict__ P_t,   // [92][100]
    const float* __restrict__ P_s,   // [92][100]
    const float* __restrict__ W_hh,  // [100][400]
    float* __restrict__ out)         // [B][100]
{
    __shared__ __attribute__((aligned(16))) float h_lds[RB][H_];
    __shared__ float gates_lds[RB][400];
    __shared__ float tg_lds[RB][H_];
    __shared__ float sg_lds[RB][H_];
    __shared__ int   loc_lds[3][RB];
    __shared__ float ts_f[RB][4][T_];            // [r][tu_s,tl_s,su_s,sl_s][t] as float
    __shared__ int   ts_i[RB][4][T_];            // [r][tu,  tl,  su,  sl  ][t]
    __shared__ float Pt_lds[92 * H_];
    __shared__ float Ps_lds[92 * H_];

    const int tid = threadIdx.x;
    const int b0  = blockIdx.x * RB;
    int steps = traj_len_p[0] + 1;
    if (steps > T_) steps = T_;

    // ---- one-time staging ----
    for (int i = tid; i < 92 * H_; i += NT) { Pt_lds[i] = P_t[i]; Ps_lds[i] = P_s[i]; }
    for (int i = tid; i < RB * 4 * T_; i += NT) {
        const int r   = i / (4 * T_);
        const int rem = i - r * (4 * T_);
        const int a   = rem / T_;
        const int t   = rem - a * T_;
        const int off = (b0 + r) * T_ + t;
        const int* fs = (a == 0) ? tu_slot : (a == 1) ? tl_slot : (a == 2) ? su_slot : sl_slot;
        const int* is = (a == 0) ? tu      : (a == 1) ? tl      : (a == 2) ? su      : sl;
        ts_f[r][a][t] = (float)fs[off];
        ts_i[r][a][t] = is[off];
    }

    // W_hh column -> register pairs (persist across all 256 steps)
    f32x2 w2[50];
    if (tid < 400) {
        #pragma unroll
        for (int j = 0; j < 50; ++j) {
            w2[j].x = W_hh[(2 * j)     * 400 + tid];
            w2[j].y = W_hh[(2 * j + 1) * 400 + tid];
        }
        ((float*)h_lds)[tid] = 0.f;
    }
    if (tid < RB) {
        loc_lds[0][tid] = traj[(b0 + tid) * T_];
        loc_lds[1][tid] = traj[(b0 + tid) * T_ + ((steps > 1) ? 1 : 0)];
    }

    // ---- role constants ----
    const bool isTS = (tid >= 448 && tid < 648);
    const int  ch   = tid - 448;          // 0..199 when isTS
    const bool is_t = ch < 100;
    const int  hx   = is_t ? ch : ch - 100;
    const int  fa   = is_t ? 0 : 2;       // ts_f/ts_i array base
    const float* Pq = is_t ? Pt_lds : Ps_lds;
    const int  gcol = (is_t ? 400 : 500) + hx;
    float* dst      = is_t ? &tg_lds[0][0] : &sg_lds[0][0];

    const int er = tid / 100;        // epilogue row   (valid for tid<400)
    const int eh = tid - er * 100;   // epilogue h-idx

    // ---- prologue: step-0 gathers straight from traj ----
    float gacc_cur[RB];
    if (tid < 400) {
        #pragma unroll
        for (int r = 0; r < RB; ++r) {
            const int loc0 = __builtin_amdgcn_readfirstlane(traj[(b0 + r) * T_]);
            gacc_cur[r] = P[(size_t)loc0 * NC + tid];
        }
    }
    float gp_cur[RB];
    if (isTS) {
        #pragma unroll
        for (int r = 0; r < RB; ++r) {
            const int loc0 = __builtin_amdgcn_readfirstlane(traj[(b0 + r) * T_]);
            gp_cur[r] = P[(size_t)loc0 * NC + gcol];
        }
    }

    float c_reg = 0.f, hval = 0.f;
    int i0 = 0, i1 = 1, i2 = 2;          // slots: loc[t], loc[t+1], loc[t+2]-dest
    __syncthreads();

    for (int t = 0; t < steps; ++t) {
        if (tid >= 700) {                       // write loc[t+2] into the dead slot
            const int r  = tid - 700;
            const int t2 = (t + 2 < steps) ? t + 2 : steps - 1;
            loc_lds[i2][r] = traj[(b0 + r) * T_ + t2];
        }

        if (tid < 400) {                        // ---- gates ----
            const int n = tid;
            // prefetch next step's gather (full step of latency cover)
            float gacc_nxt[RB];
            #pragma unroll
            for (int r = 0; r < RB; ++r) {
                const int locN = __builtin_amdgcn_readfirstlane(loc_lds[i1][r]);
                gacc_nxt[r] = P[(size_t)locN * NC + n];
            }
            // h @ W_hh (packed FP32)
            f32x2 acc2[RB];
            #pragma unroll
            for (int r = 0; r < RB; ++r) acc2[r] = (f32x2){0.f, 0.f};
            #pragma unroll
            for (int k4 = 0; k4 < H_ / 4; ++k4) {
                #pragma unroll
                for (int r = 0; r < RB; ++r) {
                    const float4 hv = *(const float4*)(&h_lds[r][k4 * 4]);
                    const f32x2 hlo = {hv.x, hv.y};
                    const f32x2 hhi = {hv.z, hv.w};
                    acc2[r] = hlo * w2[2 * k4]     + acc2[r];   // v_pk_fma_f32
                    acc2[r] = hhi * w2[2 * k4 + 1] + acc2[r];   // v_pk_fma_f32
                }
            }
            const bool isg = (n >= 200 && n < 300);   // g-gate -> tanh via 2*sig(2x)-1
            #pragma unroll
            for (int r = 0; r < RB; ++r) {
                float v  = (acc2[r].x + acc2[r].y) + gacc_cur[r];
                float xx = isg ? 2.f * v : v;
                float s  = fsig(xx);
                gates_lds[r][n] = isg ? (2.f * s - 1.f) : s;
            }
            #pragma unroll
            for (int r = 0; r < RB; ++r) gacc_cur[r] = gacc_nxt[r];
        }

        if (isTS) {                             // ---- t/s gates: all LDS-local ----
            #pragma unroll
            for (int r = 0; r < RB; ++r) {
                const float up = ts_f[r][fa][t];
                const float lo = ts_f[r][fa + 1][t];
                const int   ui = ts_i[r][fa][t];
                const int   li = ts_i[r][fa + 1][t];
                const float inv = __builtin_amdgcn_rcpf(fmaxf(up + lo, 1.f));
                const float iv  = (up * Pq[li * H_ + hx] + lo * Pq[ui * H_ + hx]) * inv;
                dst[r * H_ + hx] = fsig(gp_cur[r] + iv);
            }
            // prefetch next step's gp gather
            #pragma unroll
            for (int r = 0; r < RB; ++r) {
                const int locN = __builtin_amdgcn_readfirstlane(loc_lds[i1][r]);
                gp_cur[r] = P[(size_t)locN * NC + gcol];
            }
        }
        __syncthreads();

        if (tid < 400) {                        // ---- epilogue: c,h update ----
            float i_g = gates_lds[er][eh];
            float f_g = gates_lds[er][100 + eh];
            float g_g = gates_lds[er][200 + eh];
            float o_g = gates_lds[er][300 + eh];
            float tsg = tg_lds[er][eh] * sg_lds[er][eh];
            c_reg = f_g * c_reg + i_g * tsg * g_g;
            hval  = o_g * (2.f * fsig(2.f * c_reg) - 1.f);   // tanh = 2*sig(2x)-1
            h_lds[er][eh] = hval;
        }
        __syncthreads();

        const int tmp = i0; i0 = i1; i1 = i2; i2 = tmp;   // rotate loc slots
    }

    if (tid < 400) out[b0 * H_ + tid] = hval;
}

// ---------------------------------------------------------------------------
extern "C" void kernel_launch(void* const* d_in, const int* in_sizes, int n_in,
                              void* d_out, int out_size, void* d_ws, size_t ws_size,
                              hipStream_t stream) {
    const int*   traj     = (const int*)  d_in[0];
    // d_in[1] = lennew (unused by the reference)
    const int*   traj_len = (const int*)  d_in[2];
    const int*   tu       = (const int*)  d_in[3];
    const int*   tl       = (const int*)  d_in[4];
    const int*   tu_slot  = (const int*)  d_in[5];
    const int*   tl_slot  = (const int*)  d_in[6];
    const int*   su       = (const int*)  d_in[7];
    const int*   sl       = (const int*)  d_in[8];
    const int*   su_slot  = (const int*)  d_in[9];
    const int*   sl_slot  = (const int*)  d_in[10];
    const float* emb_loc  = (const float*)d_in[11];
    const float* emb_t    = (const float*)d_in[12];
    const float* emb_s    = (const float*)d_in[13];
    const float* W_ih     = (const float*)d_in[14];
    const float* W_hh     = (const float*)d_in[15];
    const float* b        = (const float*)d_in[16];
    const float* W_xt     = (const float*)d_in[17];
    const float* W_tt     = (const float*)d_in[18];
    const float* b_t      = (const float*)d_in[19];
    const float* W_xs     = (const float*)d_in[20];
    const float* W_ss     = (const float*)d_in[21];
    const float* b_s      = (const float*)d_in[22];

    float* P   = (float*)d_ws;              // 40001*600 = 24,000,600 floats (96.0 MB)
    float* P_t = P + (size_t)LOCN * NC;     // 9200 floats
    float* P_s = P_t + 92 * H_;             // 9200 floats

    proj_loc_kernel<<<(LOCN + PROWS - 1) / PROWS, 320, 0, stream>>>(
        emb_loc, W_ih, W_xt, W_xs, b, b_t, b_s, P);
    proj_ts_kernel<<<(2 * 92 * H_ + 255) / 256, 256, 0, stream>>>(
        emb_t, emb_s, W_tt, W_ss, P_t, P_s);
    lstm_rec_kernel<<<B_ / RB, NT, 0, stream>>>(
        traj, traj_len, tu, tl, tu_slot, tl_slot, su, sl, su_slot, sl_slot,
        P, P_t, P_s, W_hh, (float*)d_out);
}

// Round 13
// 723.179 us; speedup vs baseline: 1.6996x; 1.6996x over previous
//
#include <hip/hip_runtime.h>

#define B_    1024
#define T_    256
#define LOCN  40001
#define E_    100
#define H_    100
#define NC    600   // [0,400): gates (i|f|g|o) preact, [400,500): t preact, [500,600): s preact

typedef float f32x2 __attribute__((ext_vector_type(2)));

// Fast sigmoid: rcp(1 + exp2(-x*log2e)). v_exp_f32 + v_rcp_f32 are ~1 ulp.
__device__ __forceinline__ float fsig(float x) {
    const float e = __builtin_amdgcn_exp2f(x * -1.442695040888963f);
    return __builtin_amdgcn_rcpf(1.f + e);
}

// ---------------------------------------------------------------------------
// Kernel 1: P_loc[LOC][600] = emb_loc @ [W_ih | W_xt | W_xs] + [b | b_t | b_s]
// ROUND-13 rewrite (lstm is at its structural floor; the ~150 us residual is
// THIS kernel). Old version: 1 col/thread, scalar FMA, 16 LDS-broadcast
// floats per k per thread -> LDS-traffic + issue bound (~130 us). New:
// 4 cols/thread (150 compute threads), W fetched as one float4/k (the
// 400/500 matrix splits are x4 so a quad never straddles), accumulators as
// f32x2 pairs -> v_pk_fma_f32. Per k: 1 global b128 + 4 LDS b128 + 32 pk-FMA
// = 4x FMA/LDS-read, 2x FLOP/issue. Per-column k-order unchanged -> proj
// results bit-identical. Roofline ~35-50 us.
// ---------------------------------------------------------------------------
constexpr int PROWS = 16;
constexpr int PPAD  = 20;   // 20 floats = 80 B row stride (16B-aligned, non-pow2)
constexpr int PB    = 256;

__global__ __launch_bounds__(PB) void proj_loc_kernel(
    const float* __restrict__ emb_loc,
    const float* __restrict__ W_ih,   // [100][400]
    const float* __restrict__ W_xt,   // [100][100]
    const float* __restrict__ W_xs,   // [100][100]
    const float* __restrict__ b,      // [400]
    const float* __restrict__ b_t,    // [100]
    const float* __restrict__ b_s,    // [100]
    float* __restrict__ P)            // [LOC][600]
{
    __shared__ __attribute__((aligned(16))) float aT[E_][PPAD];  // transposed tile
    const int tid  = threadIdx.x;
    const int row0 = blockIdx.x * PROWS;

    for (int i = tid; i < PROWS * E_; i += PB) {
        const int r = i / E_, k = i - r * E_;
        const int rr = row0 + r;
        aT[k][r] = (rr < LOCN) ? emb_loc[rr * E_ + k] : 0.f;
    }
    __syncthreads();
    if (tid >= 150) return;

    const int c = tid * 4;            // owned column quad
    const float* wp; int stride; const float* bp;
    if (c < 400)      { wp = W_ih + c;         stride = 400; bp = b   + c;       }
    else if (c < 500) { wp = W_xt + (c - 400); stride = 100; bp = b_t + c - 400; }
    else              { wp = W_xs + (c - 500); stride = 100; bp = b_s + c - 500; }

    const float4 bias = *(const float4*)bp;
    f32x2 a01[PROWS], a23[PROWS];     // cols (c,c+1) and (c+2,c+3) per row
    #pragma unroll
    for (int r = 0; r < PROWS; ++r) {
        a01[r] = (f32x2){bias.x, bias.y};
        a23[r] = (f32x2){bias.z, bias.w};
    }

    #pragma unroll 2
    for (int k = 0; k < E_; ++k) {
        const float4 wv = *(const float4*)(wp + (size_t)k * stride);
        const f32x2 w01 = {wv.x, wv.y};
        const f32x2 w23 = {wv.z, wv.w};
        #pragma unroll
        for (int r4 = 0; r4 < PROWS / 4; ++r4) {
            const float4 hv = *(const float4*)(&aT[k][r4 * 4]);
            const f32x2 h0 = {hv.x, hv.x};
            const f32x2 h1 = {hv.y, hv.y};
            const f32x2 h2 = {hv.z, hv.z};
            const f32x2 h3 = {hv.w, hv.w};
            a01[r4 * 4 + 0] = h0 * w01 + a01[r4 * 4 + 0];   // v_pk_fma_f32
            a23[r4 * 4 + 0] = h0 * w23 + a23[r4 * 4 + 0];
            a01[r4 * 4 + 1] = h1 * w01 + a01[r4 * 4 + 1];
            a23[r4 * 4 + 1] = h1 * w23 + a23[r4 * 4 + 1];
            a01[r4 * 4 + 2] = h2 * w01 + a01[r4 * 4 + 2];
            a23[r4 * 4 + 2] = h2 * w23 + a23[r4 * 4 + 2];
            a01[r4 * 4 + 3] = h3 * w01 + a01[r4 * 4 + 3];
            a23[r4 * 4 + 3] = h3 * w23 + a23[r4 * 4 + 3];
        }
    }

    #pragma unroll
    for (int r = 0; r < PROWS; ++r) {
        const int rr = row0 + r;
        if (rr < LOCN) {
            float4 o;
            o.x = a01[r].x; o.y = a01[r].y; o.z = a23[r].x; o.w = a23[r].y;
            *(float4*)(&P[(size_t)rr * NC + c]) = o;
        }
    }
}

// ---------------------------------------------------------------------------
// Kernel 2: P_t[92][100] = emb_t @ W_tt ; P_s[92][100] = emb_s @ W_ss
// ---------------------------------------------------------------------------
__global__ void proj_ts_kernel(
    const float* __restrict__ emb_t, const float* __restrict__ emb_s,
    const float* __restrict__ W_tt,  const float* __restrict__ W_ss,
    float* __restrict__ P_t, float* __restrict__ P_s)
{
    int idx = blockIdx.x * 256 + threadIdx.x;
    if (idx >= 2 * 92 * H_) return;
    int which = idx / (92 * H_);
    int rem   = idx - which * (92 * H_);
    int r = rem / H_, c = rem - r * H_;
    const float* e = which ? emb_s : emb_t;
    const float* W = which ? W_ss : W_tt;
    float acc = 0.f;
    #pragma unroll
    for (int k = 0; k < 12; ++k) acc += e[r * 12 + k] * W[k * H_ + c];
    (which ? P_s : P_t)[rem] = acc;
}

// ---------------------------------------------------------------------------
// Kernel 3: the recurrence. BYTE-IDENTICAL to round 10 (619 us). Settled by
// R7-R12: VALU-count fixed (fsig + pk-FMA, 277 VALU-us), and every structural
// change (TLP, k-split, cc=2, LDS-W, latency staging, asm barriers) regressed
// -- this 2-barrier lockstep frame is the recurrence's floor (~5800 cyc/step).
// ---------------------------------------------------------------------------
constexpr int RB = 4;
constexpr int NT = 704;

__global__ __launch_bounds__(NT, 3) void lstm_rec_kernel(
    const int* __restrict__ traj,
    const int* __restrict__ traj_len_p,
    const int* __restrict__ tu,      const int* __restrict__ tl,
    const int* __restrict__ tu_slot, const int* __restrict__ tl_slot,
    const int* __restrict__ su,      const int* __restrict__ sl,
    const int* __restrict__ su_slot, const int* __restrict__ sl_slot,
    const float* __restrict__ P,     // [LOC][600]
    const float* __restrict__ P_t,   // [92][100]
    const float* __restrict__ P_s,   // [92][100]
    const float* __restrict__ W_hh,  // [100][400]
    float* __restrict__ out)         // [B][100]
{
    __shared__ __attribute__((aligned(16))) float h_lds[RB][H_];
    __shared__ float gates_lds[RB][400];
    __shared__ float tg_lds[RB][H_];
    __shared__ float sg_lds[RB][H_];
    __shared__ int   loc_lds[2][RB];

    const int tid = threadIdx.x;
    const int b0  = blockIdx.x * RB;
    int steps = traj_len_p[0] + 1;
    if (steps > T_) steps = T_;

    // W_hh column -> register pairs (persist across all 256 steps)
    f32x2 w2[50];
    if (tid < 400) {
        #pragma unroll
        for (int j = 0; j < 50; ++j) {
            w2[j].x = W_hh[(2 * j)     * 400 + tid];
            w2[j].y = W_hh[(2 * j + 1) * 400 + tid];
        }
        ((float*)h_lds)[tid] = 0.f;
    }
    if (tid < RB) loc_lds[0][tid] = traj[(b0 + tid) * T_];

    const int er = tid / 100;        // epilogue row   (valid for tid<400)
    const int eh = tid - er * 100;   // epilogue h-idx
    float c_reg = 0.f, hval = 0.f;
    __syncthreads();

    for (int t = 0; t < steps; ++t) {
        const int buf = t & 1;

        if (tid >= 700) {                       // prefetch next step's locations
            int r = tid - 700;
            if (t + 1 < steps) loc_lds[buf ^ 1][r] = traj[(b0 + r) * T_ + t + 1];
        }

        if (tid < 400) {                        // ---- gates: gather + h @ W_hh ----
            const int n = tid;
            float gacc[RB];
            #pragma unroll
            for (int r = 0; r < RB; ++r) {
                const int loc = __builtin_amdgcn_readfirstlane(loc_lds[buf][r]);
                const float* __restrict__ Prow = P + (size_t)loc * NC;  // SGPR base
                gacc[r] = Prow[n];
            }

            f32x2 acc2[RB];
            #pragma unroll
            for (int r = 0; r < RB; ++r) acc2[r] = (f32x2){0.f, 0.f};
            #pragma unroll
            for (int k4 = 0; k4 < H_ / 4; ++k4) {
                #pragma unroll
                for (int r = 0; r < RB; ++r) {
                    const float4 hv = *(const float4*)(&h_lds[r][k4 * 4]);
                    const f32x2 hlo = {hv.x, hv.y};
                    const f32x2 hhi = {hv.z, hv.w};
                    acc2[r] = hlo * w2[2 * k4]     + acc2[r];   // v_pk_fma_f32
                    acc2[r] = hhi * w2[2 * k4 + 1] + acc2[r];   // v_pk_fma_f32
                }
            }
            const bool isg = (n >= 200 && n < 300);   // g-gate -> tanh via 2*sig(2x)-1
            #pragma unroll
            for (int r = 0; r < RB; ++r) {
                float v  = (acc2[r].x + acc2[r].y) + gacc[r];
                float xx = isg ? 2.f * v : v;
                float s  = fsig(xx);
                gates_lds[r][n] = isg ? (2.f * s - 1.f) : s;
            }
        }

        if (tid >= 448 && tid < 648) {          // ---- t/s gates (h-independent) ----
            const int  ch   = tid - 448;        // 0..199
            const bool is_t = ch < 100;
            const int  hx   = is_t ? ch : ch - 100;
            const int* up_a = is_t ? tu_slot : su_slot;
            const int* lo_a = is_t ? tl_slot : sl_slot;
            const int* ui_a = is_t ? tu : su;
            const int* li_a = is_t ? tl : sl;
            const float* Pq = is_t ? P_t : P_s;
            float* dst      = is_t ? &tg_lds[0][0] : &sg_lds[0][0];
            #pragma unroll
            for (int r = 0; r < RB; ++r) {
                const int off = __builtin_amdgcn_readfirstlane((b0 + r) * T_ + t);
                const int loc = __builtin_amdgcn_readfirstlane(loc_lds[buf][r]);
                const float* __restrict__ Prow = P + (size_t)loc * NC;  // SGPR base
                float gp  = Prow[400 + ch];
                float up  = (float)up_a[off];
                float low = (float)lo_a[off];
                int   ui  = ui_a[off], li = li_a[off];
                // interp @ W = (up*Pq[low_idx] + low*Pq[up_idx]) * rcp(max(up+low,1))
                const float inv = __builtin_amdgcn_rcpf(fmaxf(up + low, 1.f));
                float iv  = (up * Pq[li * H_ + hx] + low * Pq[ui * H_ + hx]) * inv;
                float pre = gp + iv;
                dst[r * H_ + hx] = fsig(pre);
            }
        }
        __syncthreads();

        if (tid < 400) {                        // ---- epilogue: c,h update ----
            float i_g = gates_lds[er][eh];
            float f_g = gates_lds[er][100 + eh];
            float g_g = gates_lds[er][200 + eh];
            float o_g = gates_lds[er][300 + eh];
            float tsg = tg_lds[er][eh] * sg_lds[er][eh];
            c_reg = f_g * c_reg + i_g * tsg * g_g;
            hval  = o_g * (2.f * fsig(2.f * c_reg) - 1.f);   // tanh = 2*sig(2x)-1
            h_lds[er][eh] = hval;
        }
        __syncthreads();
    }

    if (tid < 400) out[b0 * H_ + tid] = hval;
}

// ---------------------------------------------------------------------------
extern "C" void kernel_launch(void* const* d_in, const int* in_sizes, int n_in,
                              void* d_out, int out_size, void* d_ws, size_t ws_size,
                              hipStream_t stream) {
    const int*   traj     = (const int*)  d_in[0];
    // d_in[1] = lennew (unused by the reference)
    const int*   traj_len = (const int*)  d_in[2];
    const int*   tu       = (const int*)  d_in[3];
    const int*   tl       = (const int*)  d_in[4];
    const int*   tu_slot  = (const int*)  d_in[5];
    const int*   tl_slot  = (const int*)  d_in[6];
    const int*   su       = (const int*)  d_in[7];
    const int*   sl       = (const int*)  d_in[8];
    const int*   su_slot  = (const int*)  d_in[9];
    const int*   sl_slot  = (const int*)  d_in[10];
    const float* emb_loc  = (const float*)d_in[11];
    const float* emb_t    = (const float*)d_in[12];
    const float* emb_s    = (const float*)d_in[13];
    const float* W_ih     = (const float*)d_in[14];
    const float* W_hh     = (const float*)d_in[15];
    const float* b        = (const float*)d_in[16];
    const float* W_xt     = (const float*)d_in[17];
    const float* W_tt     = (const float*)d_in[18];
    const float* b_t      = (const float*)d_in[19];
    const float* W_xs     = (const float*)d_in[20];
    const float* W_ss     = (const float*)d_in[21];
    const float* b_s      = (const float*)d_in[22];

    float* P   = (float*)d_ws;              // 40001*600 = 24,000,600 floats (96.0 MB)
    float* P_t = P + (size_t)LOCN * NC;     // 9200 floats
    float* P_s = P_t + 92 * H_;             // 9200 floats

    proj_loc_kernel<<<(LOCN + PROWS - 1) / PROWS, PB, 0, stream>>>(
        emb_loc, W_ih, W_xt, W_xs, b, b_t, b_s, P);
    proj_ts_kernel<<<(2 * 92 * H_ + 255) / 256, 256, 0, stream>>>(
        emb_t, emb_s, W_tt, W_ss, P_t, P_s);
    lstm_rec_kernel<<<B_ / RB, NT, 0, stream>>>(
        traj, traj_len, tu, tl, tu_slot, tl_slot, su, sl, su_slot, sl_slot,
        P, P_t, P_s, W_hh, (float*)d_out);
}